// Round 1
// baseline (297.171 us; speedup 1.0000x reference)
//
#include <hip/hip_runtime.h>

#define BATCH_N 256
#define IN_F    16384
#define OUT_F   16384

// ---------------- binning ----------------

__global__ void hist_kernel(const int* __restrict__ rows, int nnz,
                            int* __restrict__ counts) {
    int i = blockIdx.x * blockDim.x + threadIdx.x;
    if (i < nnz) atomicAdd(&counts[rows[i]], 1);
}

// exclusive scan of 16384 counts with a single 1024-thread block
__global__ void scan_kernel(const int* __restrict__ counts,
                            int* __restrict__ start,
                            int* __restrict__ cursor) {
    __shared__ int sums[1024];
    int t = threadIdx.x;
    int base = t * 16;
    int local[16];
    int s = 0;
#pragma unroll
    for (int k = 0; k < 16; ++k) { local[k] = s; s += counts[base + k]; }
    sums[t] = s;
    __syncthreads();
    for (int off = 1; off < 1024; off <<= 1) {
        int v = (t >= off) ? sums[t - off] : 0;
        __syncthreads();
        sums[t] += v;
        __syncthreads();
    }
    int prefix = (t > 0) ? sums[t - 1] : 0;
#pragma unroll
    for (int k = 0; k < 16; ++k) {
        int v = prefix + local[k];
        start[base + k] = v;
        cursor[base + k] = v;
    }
}

__global__ void scatter_kernel(const int* __restrict__ rows,
                               const int* __restrict__ cols,
                               const float* __restrict__ vals, int nnz,
                               int* __restrict__ cursor,
                               int2* __restrict__ edges) {
    int i = blockIdx.x * blockDim.x + threadIdx.x;
    if (i < nnz) {
        int r = rows[i];
        int p = atomicAdd(&cursor[r], 1);
        edges[p] = make_int2(cols[i], __float_as_int(vals[i]));
    }
}

// ---------------- transposes ----------------

// x [BATCH][IN] -> xT [IN][BATCH]
__global__ void transpose_x_kernel(const float* __restrict__ x,
                                   float* __restrict__ xT) {
    __shared__ float tile[64][65];
    int i0 = blockIdx.x * 64;           // feature tile
    int b0 = blockIdx.y * 64;           // batch tile
    int tx = threadIdx.x & 63;
    int ty = threadIdx.x >> 6;          // 0..3
#pragma unroll
    for (int k = 0; k < 64; k += 4)
        tile[ty + k][tx] = x[(b0 + ty + k) * IN_F + (i0 + tx)];
    __syncthreads();
#pragma unroll
    for (int k = 0; k < 64; k += 4)
        xT[(i0 + ty + k) * BATCH_N + (b0 + tx)] = tile[tx][ty + k];
}

// outT [OUT][BATCH] -> out [BATCH][OUT]
__global__ void transpose_out_kernel(const float* __restrict__ outT,
                                     float* __restrict__ out) {
    __shared__ float tile[64][65];
    int o0 = blockIdx.x * 64;
    int b0 = blockIdx.y * 64;
    int tx = threadIdx.x & 63;
    int ty = threadIdx.x >> 6;
#pragma unroll
    for (int k = 0; k < 64; k += 4)
        tile[ty + k][tx] = outT[(o0 + ty + k) * BATCH_N + (b0 + tx)];
    __syncthreads();
#pragma unroll
    for (int k = 0; k < 64; k += 4)
        out[(b0 + ty + k) * OUT_F + (o0 + tx)] = tile[tx][ty + k];
}

// ---------------- main accumulate ----------------
// one 64-thread block per output feature; float4 = 4 batches per lane
__global__ void accum_kernel(const float4* __restrict__ xT4,   // [IN][64]
                             const int2*  __restrict__ edges,  // packed (col, valbits)
                             const int*   __restrict__ start,
                             const int*   __restrict__ counts,
                             const float* __restrict__ bias,
                             float4* __restrict__ outT4) {     // [OUT][64]
    int o = blockIdx.x;
    int t = threadIdx.x;   // 0..63
    int s = start[o];
    int n = counts[o];
    float4 acc = make_float4(0.f, 0.f, 0.f, 0.f);
    int j = 0;
    for (; j + 4 <= n; j += 4) {
        int2 e0 = edges[s + j + 0];
        int2 e1 = edges[s + j + 1];
        int2 e2 = edges[s + j + 2];
        int2 e3 = edges[s + j + 3];
        float4 x0 = xT4[e0.x * 64 + t];
        float4 x1 = xT4[e1.x * 64 + t];
        float4 x2 = xT4[e2.x * 64 + t];
        float4 x3 = xT4[e3.x * 64 + t];
        float v0 = __int_as_float(e0.y);
        float v1 = __int_as_float(e1.y);
        float v2 = __int_as_float(e2.y);
        float v3 = __int_as_float(e3.y);
        acc.x += x0.x * v0; acc.y += x0.y * v0; acc.z += x0.z * v0; acc.w += x0.w * v0;
        acc.x += x1.x * v1; acc.y += x1.y * v1; acc.z += x1.z * v1; acc.w += x1.w * v1;
        acc.x += x2.x * v2; acc.y += x2.y * v2; acc.z += x2.z * v2; acc.w += x2.w * v2;
        acc.x += x3.x * v3; acc.y += x3.y * v3; acc.z += x3.z * v3; acc.w += x3.w * v3;
    }
    for (; j < n; ++j) {
        int2 e = edges[s + j];
        float4 xv = xT4[e.x * 64 + t];
        float v = __int_as_float(e.y);
        acc.x += xv.x * v; acc.y += xv.y * v; acc.z += xv.z * v; acc.w += xv.w * v;
    }
    float bv = bias[o];
    acc.x += bv; acc.y += bv; acc.z += bv; acc.w += bv;
    outT4[o * 64 + t] = acc;
}

extern "C" void kernel_launch(void* const* d_in, const int* in_sizes, int n_in,
                              void* d_out, int out_size, void* d_ws, size_t ws_size,
                              hipStream_t stream) {
    const float* x     = (const float*)d_in[0];
    const float* wvals = (const float*)d_in[1];
    const float* bias  = (const float*)d_in[2];
    const int*   rows  = (const int*)d_in[3];
    const int*   cols  = (const int*)d_in[4];
    float* out = (float*)d_out;
    int nnz = in_sizes[1];

    char* ws = (char*)d_ws;
    float* xT    = (float*)(ws);                                   // 16 MB
    float* outT  = (float*)(ws + (size_t)16 * 1024 * 1024);        // 16 MB
    int*   counts = (int*)(ws + (size_t)32 * 1024 * 1024);         // 64 KB
    int*   startp = counts + OUT_F;                                // 64 KB
    int*   cursor = startp + OUT_F;                                // 64 KB
    int2*  edges  = (int2*)(cursor + OUT_F);                       // 8 MB

    // ws is re-poisoned before every call: zero the histogram ourselves.
    hipMemsetAsync(counts, 0, OUT_F * sizeof(int), stream);

    transpose_x_kernel<<<dim3(IN_F / 64, BATCH_N / 64), 256, 0, stream>>>(x, xT);
    hist_kernel<<<(nnz + 255) / 256, 256, 0, stream>>>(rows, nnz, counts);
    scan_kernel<<<1, 1024, 0, stream>>>(counts, startp, cursor);
    scatter_kernel<<<(nnz + 255) / 256, 256, 0, stream>>>(rows, cols, wvals, nnz,
                                                          cursor, edges);
    accum_kernel<<<OUT_F, 64, 0, stream>>>((const float4*)xT, edges, startp,
                                           counts, bias, (float4*)outT);
    transpose_out_kernel<<<dim3(OUT_F / 64, BATCH_N / 64), 256, 0, stream>>>(outT, out);
}